// Round 1
// baseline (1018.981 us; speedup 1.0000x reference)
//
#include <hip/hip_runtime.h>
#include <cmath>
#include <cstdint>

// Instant-NGP hash encoding: N=2^20 points, D=3, 16 levels, F=2, T=2^19.
// One thread per (point, level): tid = n*16 + l  -> coalesced float2 store.

constexpr uint32_t kLog2T = 19;
constexpr uint32_t kMask  = (1u << kLog2T) - 1u;
constexpr uint32_t kP1    = 2654435761u;
constexpr uint32_t kP2    = 805459861u;

__global__ __launch_bounds__(256) void ngp_encode_kernel(
    const float* __restrict__ inp,      // [N,3]
    const float2* __restrict__ tbl,     // [16, 2^19] of float2
    float2* __restrict__ out,           // [N,16] of float2
    unsigned long long pk0, unsigned long long pk1,
    unsigned long long pk2, unsigned long long pk3)
{
    const uint32_t tid = blockIdx.x * 256u + threadIdx.x;
    const uint32_t n = tid >> 4;
    const uint32_t l = tid & 15u;

    // resolution: 16-bit fields packed in four u64 kernel args (branch-free select)
    unsigned long long pk = (l < 8u) ? ((l < 4u) ? pk0 : pk1)
                                     : ((l < 12u) ? pk2 : pk3);
    const float r = (float)((uint32_t)(pk >> ((l & 3u) * 16u)) & 0xFFFFu);

    float x = inp[n * 3u + 0u];
    float y = inp[n * 3u + 1u];
    float z = inp[n * 3u + 2u];
    x = fminf(fmaxf(x, 0.0f), 1.0f);
    y = fminf(fmaxf(y, 0.0f), 1.0f);
    z = fminf(fmaxf(z, 0.0f), 1.0f);

    const float px = x * r, py = y * r, pz = z * r;
    const float fx = floorf(px), fy = floorf(py), fz = floorf(pz);
    const float wx = px - fx, wy = py - fy, wz = pz - fz;

    const uint32_t xi = (uint32_t)(int)fx;
    const uint32_t yi = (uint32_t)(int)fy;
    const uint32_t zi = (uint32_t)(int)fz;

    // hash components: corner = (xi+a) ^ (yi+b)*P1 ^ (zi+c)*P2  (mod 2^19)
    const uint32_t hx0 = xi,       hx1 = xi + 1u;
    const uint32_t hy0 = yi * kP1, hy1 = hy0 + kP1;
    const uint32_t hz0 = zi * kP2, hz1 = hz0 + kP2;
    const uint32_t lbase = l << kLog2T;   // fold level into gather index (uniform SGPR base)

    const float wx1 = wx, wx0 = 1.0f - wx;
    const float wy1 = wy, wy0 = 1.0f - wy;
    const float wz1 = wz, wz0 = 1.0f - wz;
    const float wyz00 = wy0 * wz0, wyz01 = wy0 * wz1;
    const float wyz10 = wy1 * wz0, wyz11 = wy1 * wz1;

    float acc0 = 0.0f, acc1 = 0.0f;
#define NGP_CORNER(A, B, C)                                       \
    {                                                             \
        uint32_t h = (hx##A ^ hy##B ^ hz##C) & kMask;             \
        float2 f = tbl[lbase + h];                                \
        float wt = wx##A * wyz##B##C;                             \
        acc0 = fmaf(wt, f.x, acc0);                               \
        acc1 = fmaf(wt, f.y, acc1);                               \
    }
    NGP_CORNER(0, 0, 0) NGP_CORNER(0, 0, 1)
    NGP_CORNER(0, 1, 0) NGP_CORNER(0, 1, 1)
    NGP_CORNER(1, 0, 0) NGP_CORNER(1, 0, 1)
    NGP_CORNER(1, 1, 0) NGP_CORNER(1, 1, 1)
#undef NGP_CORNER

    out[tid] = make_float2(acc0, acc1);
}

extern "C" void kernel_launch(void* const* d_in, const int* in_sizes, int n_in,
                              void* d_out, int out_size, void* d_ws, size_t ws_size,
                              hipStream_t stream)
{
    const float* inp  = (const float*)d_in[0];
    const float2* tbl = (const float2*)d_in[1];
    float2* out       = (float2*)d_out;

    // Replicate numpy's float64 resolution chain with host libm (glibc):
    //   b = exp((log(512)-log(16))/15); r_k = floor(16 * b**k)
    // npy_pow shortcuts: k==0 -> 1, k==1 -> b, k==2 -> b*b, else pow().
    double b = std::exp((std::log(512.0) - std::log(16.0)) / 15.0);
    unsigned long long pk[4] = {0ull, 0ull, 0ull, 0ull};
    for (int k = 0; k < 16; ++k) {
        double v;
        if (k == 0)      v = 1.0;
        else if (k == 1) v = b;
        else if (k == 2) v = b * b;
        else             v = std::pow(b, (double)k);
        unsigned long long ri = (unsigned long long)std::floor(16.0 * v);
        pk[k >> 2] |= (ri & 0xFFFFull) << ((k & 3) * 16);
    }

    const uint32_t npts  = (uint32_t)(in_sizes[0] / 3);   // 2^20
    const uint32_t total = npts * 16u;                    // threads = N*levels
    dim3 grid(total / 256u), block(256u);
    hipLaunchKernelGGL(ngp_encode_kernel, grid, block, 0, stream,
                       inp, tbl, out, pk[0], pk[1], pk[2], pk[3]);
}

// Round 3
// 728.380 us; speedup vs baseline: 1.3990x; 1.3990x over previous
//
#include <hip/hip_runtime.h>
#include <cmath>
#include <cstdint>

// Instant-NGP hash encoding: N=2^20 points, D=3, 16 levels, F=2, T=2^19.
// Level-major two-pass: pass1 encodes one level per 4096-block slab so the
// in-flight working set is a single 4MB table (L2-resident per XCD);
// pass2 transposes [L][N] -> [N][L] via LDS with coalesced IO.

constexpr uint32_t kLog2T = 19;
constexpr uint32_t kMask  = (1u << kLog2T) - 1u;
constexpr uint32_t kP1    = 2654435761u;
constexpr uint32_t kP2    = 805459861u;
constexpr uint32_t kN     = 1u << 20;
constexpr uint32_t kL     = 16;

typedef float v2f __attribute__((ext_vector_type(2)));   // nt-builtin-compatible

template <bool DIRECT>
__global__ __launch_bounds__(256) void ngp_encode_lm_kernel(
    const float* __restrict__ inp,      // [N,3]
    const v2f* __restrict__ tbl,        // [16, 2^19] of float2
    v2f* __restrict__ dst,              // DIRECT: [N,16]; else ws [16,N]
    unsigned long long pk0, unsigned long long pk1,
    unsigned long long pk2, unsigned long long pk3)
{
    const uint32_t b = blockIdx.x;
    const uint32_t l = b >> 12;                         // level-major in time
    const uint32_t n = ((b & 4095u) << 8) + threadIdx.x;

    unsigned long long pk = (l < 8u) ? ((l < 4u) ? pk0 : pk1)
                                     : ((l < 12u) ? pk2 : pk3);
    const float r = (float)((uint32_t)(pk >> ((l & 3u) * 16u)) & 0xFFFFu);

    // nt loads: keep streaming point data out of L2 (reserve L2 for the table)
    float x = __builtin_nontemporal_load(inp + n * 3u + 0u);
    float y = __builtin_nontemporal_load(inp + n * 3u + 1u);
    float z = __builtin_nontemporal_load(inp + n * 3u + 2u);
    x = fminf(fmaxf(x, 0.0f), 1.0f);
    y = fminf(fmaxf(y, 0.0f), 1.0f);
    z = fminf(fmaxf(z, 0.0f), 1.0f);

    const float px = x * r, py = y * r, pz = z * r;
    const float fx = floorf(px), fy = floorf(py), fz = floorf(pz);
    const float wx = px - fx, wy = py - fy, wz = pz - fz;

    const uint32_t xi = (uint32_t)(int)fx;
    const uint32_t yi = (uint32_t)(int)fy;
    const uint32_t zi = (uint32_t)(int)fz;

    const uint32_t hx0 = xi,       hx1 = xi + 1u;
    const uint32_t hy0 = yi * kP1, hy1 = hy0 + kP1;
    const uint32_t hz0 = zi * kP2, hz1 = hz0 + kP2;
    const uint32_t lbase = l << kLog2T;

    const float wx1 = wx, wx0 = 1.0f - wx;
    const float wy1 = wy, wy0 = 1.0f - wy;
    const float wz1 = wz, wz0 = 1.0f - wz;
    const float wyz00 = wy0 * wz0, wyz01 = wy0 * wz1;
    const float wyz10 = wy1 * wz0, wyz11 = wy1 * wz1;

    float acc0 = 0.0f, acc1 = 0.0f;
#define NGP_CORNER(A, B, C)                                       \
    {                                                             \
        uint32_t h = (hx##A ^ hy##B ^ hz##C) & kMask;             \
        v2f f = tbl[lbase + h];                                   \
        float wt = wx##A * wyz##B##C;                             \
        acc0 = fmaf(wt, f.x, acc0);                               \
        acc1 = fmaf(wt, f.y, acc1);                               \
    }
    NGP_CORNER(0, 0, 0) NGP_CORNER(0, 0, 1)
    NGP_CORNER(0, 1, 0) NGP_CORNER(0, 1, 1)
    NGP_CORNER(1, 0, 0) NGP_CORNER(1, 0, 1)
    NGP_CORNER(1, 1, 0) NGP_CORNER(1, 1, 1)
#undef NGP_CORNER

    v2f res; res.x = acc0; res.y = acc1;
    if (DIRECT) {
        __builtin_nontemporal_store(res, dst + (n * kL + l));   // strided fallback
    } else {
        __builtin_nontemporal_store(res, dst + (l * kN + n));   // coalesced
    }
}

// Transpose ws[16][N] -> out[N][16] (float2 elements), 64 points per block.
__global__ __launch_bounds__(256) void ngp_transpose_kernel(
    const v2f* __restrict__ ws, v2f* __restrict__ out)
{
    __shared__ v2f tile[kL * 65];        // pad 64->65: kills phase-2 conflicts
    const uint32_t t  = threadIdx.x;
    const uint32_t n0 = blockIdx.x * 64u;

    // load: 4 iters x (4 levels x 64 points), coalesced 512B rows
    #pragma unroll
    for (uint32_t it = 0; it < 4; ++it) {
        const uint32_t l = it * 4u + (t >> 6);
        const uint32_t p = t & 63u;
        tile[l * 65u + p] = __builtin_nontemporal_load(ws + l * kN + n0 + p);
    }
    __syncthreads();

    // store: 4 iters x (16 points x 16 levels), consecutive float2 addresses
    #pragma unroll
    for (uint32_t it = 0; it < 4; ++it) {
        const uint32_t p = it * 16u + (t >> 4);
        const uint32_t l = t & 15u;
        __builtin_nontemporal_store(tile[l * 65u + p], out + (n0 + p) * kL + l);
    }
}

extern "C" void kernel_launch(void* const* d_in, const int* in_sizes, int n_in,
                              void* d_out, int out_size, void* d_ws, size_t ws_size,
                              hipStream_t stream)
{
    const float* inp = (const float*)d_in[0];
    const v2f* tbl   = (const v2f*)d_in[1];
    v2f* out         = (v2f*)d_out;

    // numpy-exact resolution table (host libm float64 chain)
    double b = std::exp((std::log(512.0) - std::log(16.0)) / 15.0);
    unsigned long long pk[4] = {0ull, 0ull, 0ull, 0ull};
    for (int k = 0; k < 16; ++k) {
        double v;
        if (k == 0)      v = 1.0;
        else if (k == 1) v = b;
        else if (k == 2) v = b * b;
        else             v = std::pow(b, (double)k);
        unsigned long long ri = (unsigned long long)std::floor(16.0 * v);
        pk[k >> 2] |= (ri & 0xFFFFull) << ((k & 3) * 16);
    }

    const uint32_t nblocks = (kN * kL) / 256u;          // 65536
    const bool have_ws = ws_size >= (size_t)kN * kL * sizeof(v2f);

    if (have_ws) {
        v2f* ws = (v2f*)d_ws;
        hipLaunchKernelGGL((ngp_encode_lm_kernel<false>), dim3(nblocks), dim3(256), 0, stream,
                           inp, tbl, ws, pk[0], pk[1], pk[2], pk[3]);
        hipLaunchKernelGGL(ngp_transpose_kernel, dim3(kN / 64u), dim3(256), 0, stream,
                           ws, out);
    } else {
        hipLaunchKernelGGL((ngp_encode_lm_kernel<true>), dim3(nblocks), dim3(256), 0, stream,
                           inp, tbl, out, pk[0], pk[1], pk[2], pk[3]);
    }
}

// Round 4
// 640.275 us; speedup vs baseline: 1.5915x; 1.1376x over previous
//
#include <hip/hip_runtime.h>
#include <cmath>
#include <cstdint>

// Instant-NGP hash encoding: N=2^20 points, D=3, 16 levels, F=2, T=2^19.
// Level-major two-pass. Encode exploits hash prime_x==1: for even xi the two
// x-corners are idx and idx^1 -> one aligned 16B load covers both; odd-xi
// lanes issue the partner load under exec mask (saves ~25% of lane requests).

constexpr uint32_t kLog2T = 19;
constexpr uint32_t kMask  = (1u << kLog2T) - 1u;
constexpr uint32_t kP1    = 2654435761u;
constexpr uint32_t kP2    = 805459861u;
constexpr uint32_t kN     = 1u << 20;
constexpr uint32_t kL     = 16;

typedef float v2f __attribute__((ext_vector_type(2)));
typedef float v4f __attribute__((ext_vector_type(4)));

__device__ __forceinline__ v2f sel_half(v4f q, uint32_t hi) {
    v2f lo; lo.x = q.x; lo.y = q.y;
    v2f hi2; hi2.x = q.z; hi2.y = q.w;
    return hi ? hi2 : lo;
}

template <bool DIRECT>
__global__ __launch_bounds__(256) void ngp_encode_lm_kernel(
    const float* __restrict__ inp,      // [N,3]
    const v4f* __restrict__ tbl4,       // [16 * 2^18] entry-pairs
    v2f* __restrict__ dst,              // DIRECT: [N,16]; else ws [16,N]
    unsigned long long pk0, unsigned long long pk1,
    unsigned long long pk2, unsigned long long pk3)
{
    const uint32_t b = blockIdx.x;
    const uint32_t l = b >> 12;                         // level-major in time
    const uint32_t n = ((b & 4095u) << 8) + threadIdx.x;

    unsigned long long pk = (l < 8u) ? ((l < 4u) ? pk0 : pk1)
                                     : ((l < 12u) ? pk2 : pk3);
    const float r = (float)((uint32_t)(pk >> ((l & 3u) * 16u)) & 0xFFFFu);

    float x = __builtin_nontemporal_load(inp + n * 3u + 0u);
    float y = __builtin_nontemporal_load(inp + n * 3u + 1u);
    float z = __builtin_nontemporal_load(inp + n * 3u + 2u);
    x = fminf(fmaxf(x, 0.0f), 1.0f);
    y = fminf(fmaxf(y, 0.0f), 1.0f);
    z = fminf(fmaxf(z, 0.0f), 1.0f);

    const float px = x * r, py = y * r, pz = z * r;
    const float fx = floorf(px), fy = floorf(py), fz = floorf(pz);
    const float wx = px - fx, wy = py - fy, wz = pz - fz;

    const uint32_t xi  = (uint32_t)(int)fx;
    const uint32_t xi1 = xi + 1u;
    const uint32_t yi  = (uint32_t)(int)fy;
    const uint32_t zi  = (uint32_t)(int)fz;

    const uint32_t hy0 = yi * kP1, hy1 = hy0 + kP1;
    const uint32_t hz0 = zi * kP2, hz1 = hz0 + kP2;
    const uint32_t hyz00 = hy0 ^ hz0, hyz01 = hy0 ^ hz1;
    const uint32_t hyz10 = hy1 ^ hz0, hyz11 = hy1 ^ hz1;

    const uint32_t pb = l << (kLog2T - 1);              // pair base

    const uint32_t i000 = (xi  ^ hyz00) & kMask, i100 = (xi1 ^ hyz00) & kMask;
    const uint32_t i001 = (xi  ^ hyz01) & kMask, i101 = (xi1 ^ hyz01) & kMask;
    const uint32_t i010 = (xi  ^ hyz10) & kMask, i110 = (xi1 ^ hyz10) & kMask;
    const uint32_t i011 = (xi  ^ hyz11) & kMask, i111 = (xi1 ^ hyz11) & kMask;

    // 4 unconditional pair loads (each covers both x-corners when xi even)
    const v4f q00 = tbl4[pb + (i000 >> 1)];
    const v4f q01 = tbl4[pb + (i001 >> 1)];
    const v4f q10 = tbl4[pb + (i010 >> 1)];
    const v4f q11 = tbl4[pb + (i011 >> 1)];

    v2f f000 = sel_half(q00, i000 & 1u), f100 = sel_half(q00, (i000 & 1u) ^ 1u);
    v2f f001 = sel_half(q01, i001 & 1u), f101 = sel_half(q01, (i001 & 1u) ^ 1u);
    v2f f010 = sel_half(q10, i010 & 1u), f110 = sel_half(q10, (i010 & 1u) ^ 1u);
    v2f f011 = sel_half(q11, i011 & 1u), f111 = sel_half(q11, (i011 & 1u) ^ 1u);

    if (xi & 1u) {   // odd xi: partner corner lives in a different pair
        const v4f r00 = tbl4[pb + (i100 >> 1)];
        const v4f r01 = tbl4[pb + (i101 >> 1)];
        const v4f r10 = tbl4[pb + (i110 >> 1)];
        const v4f r11 = tbl4[pb + (i111 >> 1)];
        f100 = sel_half(r00, i100 & 1u);
        f101 = sel_half(r01, i101 & 1u);
        f110 = sel_half(r10, i110 & 1u);
        f111 = sel_half(r11, i111 & 1u);
    }

    const float wx1w = wx, wx0w = 1.0f - wx;
    const float wy1w = wy, wy0w = 1.0f - wy;
    const float wz1w = wz, wz0w = 1.0f - wz;
    const float wyz00w = wy0w * wz0w, wyz01w = wy0w * wz1w;
    const float wyz10w = wy1w * wz0w, wyz11w = wy1w * wz1w;

    float acc0 = 0.0f, acc1 = 0.0f;
#define NGP_ACC(F, W)                         \
    acc0 = fmaf((W), (F).x, acc0);            \
    acc1 = fmaf((W), (F).y, acc1);
    NGP_ACC(f000, wx0w * wyz00w) NGP_ACC(f100, wx1w * wyz00w)
    NGP_ACC(f001, wx0w * wyz01w) NGP_ACC(f101, wx1w * wyz01w)
    NGP_ACC(f010, wx0w * wyz10w) NGP_ACC(f110, wx1w * wyz10w)
    NGP_ACC(f011, wx0w * wyz11w) NGP_ACC(f111, wx1w * wyz11w)
#undef NGP_ACC

    v2f res; res.x = acc0; res.y = acc1;
    if (DIRECT) {
        __builtin_nontemporal_store(res, dst + (n * kL + l));
    } else {
        __builtin_nontemporal_store(res, dst + (l * kN + n));
    }
}

// Transpose ws[16][N] -> out[N][16] (v2f elements), 128 points per block,
// all global IO as 16B nt ops.
__global__ __launch_bounds__(256) void ngp_transpose_kernel(
    const v4f* __restrict__ ws4,      // [16][N/2]
    v4f* __restrict__ out4)           // [N][8]
{
    __shared__ v4f tile4[kL][65];     // [level][point-pair], padded
    const uint32_t t  = threadIdx.x;
    const uint32_t n0 = blockIdx.x * 128u;

    // load: 4 iters x (4 levels x 64 pairs), each row 1KB contiguous
    #pragma unroll
    for (uint32_t it = 0; it < 4; ++it) {
        const uint32_t l  = it * 4u + (t >> 6);
        const uint32_t pc = t & 63u;
        tile4[l][pc] = __builtin_nontemporal_load(ws4 + l * (kN / 2u) + (n0 >> 1) + pc);
    }
    __syncthreads();

    // store: 4 iters x (32 points x 8 level-pairs) = 16B per thread per iter
    const v2f* tv = (const v2f*)&tile4[0][0];     // row stride 130 v2f
    #pragma unroll
    for (uint32_t it = 0; it < 4; ++it) {
        const uint32_t p  = it * 32u + (t >> 3);
        const uint32_t lp = t & 7u;
        const v2f a = tv[(2u * lp + 0u) * 130u + p];
        const v2f b = tv[(2u * lp + 1u) * 130u + p];
        v4f o; o.x = a.x; o.y = a.y; o.z = b.x; o.w = b.y;
        __builtin_nontemporal_store(o, out4 + (n0 + p) * 8u + lp);
    }
}

extern "C" void kernel_launch(void* const* d_in, const int* in_sizes, int n_in,
                              void* d_out, int out_size, void* d_ws, size_t ws_size,
                              hipStream_t stream)
{
    const float* inp = (const float*)d_in[0];
    const v4f* tbl4  = (const v4f*)d_in[1];

    // numpy-exact resolution table (host libm float64 chain)
    double b = std::exp((std::log(512.0) - std::log(16.0)) / 15.0);
    unsigned long long pk[4] = {0ull, 0ull, 0ull, 0ull};
    for (int k = 0; k < 16; ++k) {
        double v;
        if (k == 0)      v = 1.0;
        else if (k == 1) v = b;
        else if (k == 2) v = b * b;
        else             v = std::pow(b, (double)k);
        unsigned long long ri = (unsigned long long)std::floor(16.0 * v);
        pk[k >> 2] |= (ri & 0xFFFFull) << ((k & 3) * 16);
    }

    const uint32_t nblocks = (kN * kL) / 256u;          // 65536
    const bool have_ws = ws_size >= (size_t)kN * kL * sizeof(v2f);

    if (have_ws) {
        hipLaunchKernelGGL((ngp_encode_lm_kernel<false>), dim3(nblocks), dim3(256), 0, stream,
                           inp, tbl4, (v2f*)d_ws, pk[0], pk[1], pk[2], pk[3]);
        hipLaunchKernelGGL(ngp_transpose_kernel, dim3(kN / 128u), dim3(256), 0, stream,
                           (const v4f*)d_ws, (v4f*)d_out);
    } else {
        hipLaunchKernelGGL((ngp_encode_lm_kernel<true>), dim3(nblocks), dim3(256), 0, stream,
                           inp, tbl4, (v2f*)d_out, pk[0], pk[1], pk[2], pk[3]);
    }
}